// Round 8
// baseline (296.866 us; speedup 1.0000x reference)
//
#include <hip/hip_runtime.h>

// MHA: B=2, S=2048, D=1024, H=16, DK=64. I/O bf16 (harness-confirmed R4);
// dual fp32 path retained via runtime detect. mask int32.
//
// Pipeline (ws 16 MB; d_out doubles as V scratch):
//   0) detect: classify d_in[0] bf16 vs fp32 -> flag in ws
//   1) gemmk<128,0>: Q/K/V proj y = x @ W^T (one launch, z selects tensor).
//        z=0: Qh [B,H,S,DK], pre-scaled by 0.125*log2e (softmax fold)
//        z=1: Kh [B,H,S,DK]
//        z=2: Vt [B,H,DK,S]  (transposed, bf16x4-packed stores)
//   2) attn: flash, K/V LDS-staged (global_load_lds w16, double-buffered,
//        XOR-swizzled), no-max exp2 softmax, P round-trip wave-private LDS.
//        128 q-rows/block (32/wave), 64 keys/iter. ctx IN PLACE over Qh.
//   3) gemmk<64,1>: out = ctx @ Wo^T -> d_out (512 blocks).
//
// MFMA 16x16x32 bf16 layouts (verified):
//   A: lane holds A[m=lane&15][k=(lane>>4)*8+j]
//   B: lane holds B[k=(lane>>4)*8+j][n=lane&15]
//   C/D: col=lane&15, row=(lane>>4)*4+reg
//
// R4: no u16/bf16 punning (TBAA reorder -> NaN).
// R5: per-wave direct global K/V = latency bound -> LDS staging.
// R6: VGPR-roundtrip staging = latency bound -> global_load_lds w16.
// R7: attn VALU-issue bound (54% busy) dominated by per-store swizzle math;
//     epilogues scatter 2B stores. -> XOR-factored hoisted P addresses
//     (addr = U[qt][r] ^ W[tt], disjoint bitfields), row-sum via MFMA with
//     B=ones, swapped-operand PV & GEMM epilogues for packed 8B/16B stores.

typedef __bf16 bf16x8 __attribute__((ext_vector_type(8)));
typedef __bf16 bf16x4 __attribute__((ext_vector_type(4)));
typedef float f32x4 __attribute__((ext_vector_type(4)));

#define B_ 2
#define S_ 2048
#define D_ 1024
#define H_ 16
#define DK_ 64
#define QSCALE 0.18033688011112042f  // 0.125 * log2(e)

// ---------------------------------------------------------------------------
__global__ void detect_dtype(const unsigned int* __restrict__ qw,
                             int* __restrict__ flag) {
  int cnt = 0;
#pragma unroll
  for (int i = 0; i < 4; ++i) {
    unsigned int w = qw[threadIdx.x + 64 * i];
    int e = (w >> 7) & 0xFF;
    cnt += (e >= 100 && e <= 140) ? 1 : 0;
  }
#pragma unroll
  for (int off = 32; off > 0; off >>= 1) cnt += __shfl_down(cnt, off, 64);
  if (threadIdx.x == 0) *flag = (cnt >= 128) ? 0 : 1;
}

__device__ __forceinline__ bf16x8 load8cvt(const void* base, size_t eoff,
                                           bool f32) {
  if (!f32) return *(const bf16x8*)((const __bf16*)base + eoff);
  const float* p = (const float*)base + eoff;
  bf16x8 r;
#pragma unroll
  for (int j = 0; j < 8; ++j) r[j] = (__bf16)p[j];
  return r;
}

// async 16B global -> LDS (lds dest = wave-uniform base + lane*16)
__device__ __forceinline__ void async_cp16(const __bf16* g, __bf16* l) {
  __builtin_amdgcn_global_load_lds(
      (const __attribute__((address_space(1))) unsigned int*)g,
      (__attribute__((address_space(3))) unsigned int*)l, 16, 0, 0);
}

// ---------------------------------------------------------------------------
// GEMM: C[M,N] = X[M,K] @ W[N,K]^T, M=4096, N=K=1024, TM x 128 tile, BK=32.
// LDS unpadded [rows][32], 16B chunks XOR-swizzled (phys = j ^ ((row>>1)&3)).
// Staging via global_load_lds w16 (bf16) / load+convert (fp32 fallback).
// K-loop: swapped operands mfma(W,X) for z0/z1/MODE1 -> C rows span n ->
// packed bf16x4 (or float4) epilogue stores. z2 (Vt) keeps mfma(X,W) with
// r spanning s -> packed along s.
// ---------------------------------------------------------------------------
template <int TM, int MODE>
__global__ __launch_bounds__(256) void gemmk(
    const void* X0, const void* X1, const void* X2,
    const void* W0, const void* W1, const void* W2,
    void* O0, void* O1, void* O2, const int* __restrict__ dflag) {
  constexpr int Kd = 1024, Nd = 1024;
  constexpr int NI = (TM == 128) ? 4 : 2;       // n 16-tiles per wave
  constexpr int ALOADS = TM / 64;
  const void* X = (blockIdx.z == 0) ? X0 : (blockIdx.z == 1 ? X1 : X2);
  const void* W = (blockIdx.z == 0) ? W0 : (blockIdx.z == 1 ? W1 : W2);
  void* O = (blockIdx.z == 0) ? O0 : (blockIdx.z == 1 ? O1 : O2);
  const bool f32io = (*dflag != 0);
  const bool vt = (MODE == 0 && blockIdx.z == 2);  // Vt orientation

  __shared__ __attribute__((aligned(16))) __bf16 As[TM * 32];
  __shared__ __attribute__((aligned(16))) __bf16 Bs[128 * 32];

  const int m0 = blockIdx.x * TM;
  const int n0 = blockIdx.y * 128;
  const int t = threadIdx.x;
  const int lane = t & 63, wave = t >> 6;
  const int l15 = lane & 15, quad = lane >> 4;
  const int wm = (TM == 128) ? (wave >> 1) * 64 : 0;
  const int wn = (TM == 128) ? (wave & 1) * 64 : wave * 32;

  const __bf16* gA[ALOADS];
  __bf16* ldsA[ALOADS];
#pragma unroll
  for (int i = 0; i < ALOADS; ++i) {
    int c = (wave * ALOADS + i) * 64 + lane;
    int row = c >> 2, j = c & 3;
    int jl = j ^ ((row >> 1) & 3);
    ldsA[i] = &As[(wave * ALOADS + i) * 512];
    if (MODE == 0) {
      gA[i] = (const __bf16*)X + (size_t)(m0 + row) * Kd + jl * 8;
    } else {
      int gm = m0 + row;
      gA[i] = (const __bf16*)X +
              (size_t)(gm >> 11) * (H_ * S_ * DK_) + (size_t)(gm & (S_ - 1)) * DK_ +
              jl * 8;
    }
  }
  const __bf16* gB[2];
  __bf16* ldsB[2];
#pragma unroll
  for (int i = 0; i < 2; ++i) {
    int c = (wave * 2 + i) * 64 + lane;
    int row = c >> 2, j = c & 3;
    int jl = j ^ ((row >> 1) & 3);
    ldsB[i] = &Bs[(wave * 2 + i) * 512];
    gB[i] = (const __bf16*)W + (size_t)(n0 + row) * Kd + jl * 8;
  }

  f32x4 acc[4 * NI] = {};  // vt: [mi][ni] mi*NI+ni; else: [pi][qi] pi*4+qi

  for (int k0 = 0; k0 < Kd; k0 += 32) {
    __syncthreads();
    if (!f32io) {
      if (MODE == 0) {
#pragma unroll
        for (int i = 0; i < ALOADS; ++i) async_cp16(gA[i] + k0, ldsA[i]);
      } else {
        const size_t koff = (size_t)(k0 >> 6) * (S_ * DK_) + (k0 & 32);
#pragma unroll
        for (int i = 0; i < ALOADS; ++i) async_cp16(gA[i] + koff, ldsA[i]);
      }
#pragma unroll
      for (int i = 0; i < 2; ++i) async_cp16(gB[i] + k0, ldsB[i]);
    } else {
#pragma unroll
      for (int i = 0; i < TM / 64; ++i) {
        int c = t + 256 * i;
        int row = c >> 2, j = c & 3;
        int jl = j ^ ((row >> 1) & 3);
        bf16x8 xv;
        if (MODE == 0) {
          xv = load8cvt(X, (size_t)(m0 + row) * Kd + k0 + jl * 8, true);
        } else {
          int gm = m0 + row, gk = k0 + jl * 8;
          xv = *(const bf16x8*)((const __bf16*)X +
                ((((size_t)(gm >> 11) * H_ + (gk >> 6)) * S_) +
                 (gm & (S_ - 1))) * DK_ + (gk & (DK_ - 1)));
        }
        *(bf16x8*)&As[row * 32 + j * 8] = xv;
      }
#pragma unroll
      for (int i = 0; i < 2; ++i) {
        int c = t + 256 * i;
        int row = c >> 2, j = c & 3;
        int jl = j ^ ((row >> 1) & 3);
        bf16x8 wv = load8cvt(W, (size_t)(n0 + row) * Kd + k0 + jl * 8, true);
        *(bf16x8*)&Bs[row * 32 + j * 8] = wv;
      }
    }
    __syncthreads();

    bf16x8 af[4], bfr[NI];
#pragma unroll
    for (int mi = 0; mi < 4; ++mi) {
      int row = wm + mi * 16 + l15;
      af[mi] = *(const bf16x8*)&As[row * 32 + ((quad ^ ((row >> 1) & 3)) << 3)];
    }
#pragma unroll
    for (int ni = 0; ni < NI; ++ni) {
      int row = wn + ni * 16 + l15;
      bfr[ni] = *(const bf16x8*)&Bs[row * 32 + ((quad ^ ((row >> 1) & 3)) << 3)];
    }
    if (vt) {
#pragma unroll
      for (int mi = 0; mi < 4; ++mi)
#pragma unroll
        for (int ni = 0; ni < NI; ++ni)
          acc[mi * NI + ni] = __builtin_amdgcn_mfma_f32_16x16x32_bf16(
              af[mi], bfr[ni], acc[mi * NI + ni], 0, 0, 0);
    } else {
#pragma unroll
      for (int pi = 0; pi < NI; ++pi)
#pragma unroll
        for (int qi = 0; qi < 4; ++qi)
          acc[pi * 4 + qi] = __builtin_amdgcn_mfma_f32_16x16x32_bf16(
              bfr[pi], af[qi], acc[pi * 4 + qi], 0, 0, 0);
    }
  }

  if (vt) {
    // Vt [B,H,DK,S]: r spans s -> bf16x4 packed along s
#pragma unroll
    for (int mi = 0; mi < 4; ++mi)
#pragma unroll
      for (int ni = 0; ni < NI; ++ni) {
        int mbase = m0 + wm + mi * 16 + quad * 4;
        int n = n0 + wn + ni * 16 + l15;
        int b = mbase >> 11, sb = mbase & (S_ - 1);
        int h = n >> 6, dk = n & (DK_ - 1);
        bf16x4 pk;
#pragma unroll
        for (int r = 0; r < 4; ++r) pk[r] = (__bf16)acc[mi * NI + ni][r];
        *(bf16x4*)&((__bf16*)O)[((size_t)(b * H_ + h) * DK_ + dk) * S_ + sb] = pk;
      }
  } else {
    const float oscale = (MODE == 0 && blockIdx.z == 0) ? QSCALE : 1.0f;
#pragma unroll
    for (int pi = 0; pi < NI; ++pi)
#pragma unroll
      for (int qi = 0; qi < 4; ++qi) {
        int nb = n0 + wn + pi * 16 + quad * 4;   // r spans n
        int m = m0 + wm + qi * 16 + l15;
        if (MODE == 0) {
          int b = m >> 11, s = m & (S_ - 1);
          int h = nb >> 6, dk = nb & (DK_ - 1);
          bf16x4 pk;
#pragma unroll
          for (int r = 0; r < 4; ++r)
            pk[r] = (__bf16)(acc[pi * 4 + qi][r] * oscale);
          *(bf16x4*)&((__bf16*)O)[((size_t)(b * H_ + h) * S_ + s) * DK_ + dk] = pk;
        } else {
          size_t idx = (size_t)m * Nd + nb;
          if (f32io) {
            *(f32x4*)&((float*)O)[idx] = acc[pi * 4 + qi];
          } else {
            bf16x4 pk;
#pragma unroll
            for (int r = 0; r < 4; ++r) pk[r] = (__bf16)acc[pi * 4 + qi][r];
            *(bf16x4*)&((__bf16*)O)[idx] = pk;
          }
        }
      }
  }
}

// ---------------------------------------------------------------------------
// Flash attention. Block = (b,h) x 128 q-rows, 4 waves x 32 q-rows, 64
// keys/iter, K/V double-buffered via global_load_lds w16, XOR-swizzled.
// P-store addresses factored as U[qt][r] ^ W[tt] (disjoint bitfields),
// hoisted out of the K-loop. Row-sum via mfma(ones, pf). PV swapped
// (mfma(vf, pf)) -> output rows span dk -> packed bf16x4 stores.
// ---------------------------------------------------------------------------
__global__ __launch_bounds__(256) void attn(
    const __bf16* Qh, const __bf16* __restrict__ Kh,
    const __bf16* __restrict__ Vt, const int* __restrict__ mask,
    __bf16* Out) {
  __shared__ __attribute__((aligned(16))) __bf16 Ks[2][4096];
  __shared__ __attribute__((aligned(16))) __bf16 Vs[2][4096];
  __shared__ __attribute__((aligned(16))) __bf16 P[4][2048];

  const int t = threadIdx.x;
  const int lane = t & 63, wave = t >> 6;
  const int l15 = lane & 15, quad = lane >> 4;
  const int qb = blockIdx.x & 15;   // 16 q-blocks of 128
  const int bh = blockIdx.x >> 4;   // b*H + h
  const int b = bh >> 4;
  const int q0 = qb * 128 + wave * 32;

  const __bf16* Q = Qh + (size_t)bh * S_ * DK_;
  const __bf16* K = Kh + (size_t)bh * S_ * DK_;
  const __bf16* V = Vt + (size_t)bh * DK_ * S_;   // [dk][s]
  const int* mk = mask + b * S_;

  bf16x8 qf[2][2];
#pragma unroll
  for (int qt = 0; qt < 2; ++qt)
#pragma unroll
    for (int h = 0; h < 2; ++h)
      qf[qt][h] = *(const bf16x8*)&Q[(size_t)(q0 + qt * 16 + l15) * DK_ +
                                     h * 32 + quad * 8];

  // hoisted P-store addresses: addr = U[qt][r] ^ Wx[tt]
  const int kl = l15 & 7, hb8 = l15 & 8;
  int U[2][4], Wx[4];
#pragma unroll
  for (int qt = 0; qt < 2; ++qt)
#pragma unroll
    for (int r = 0; r < 4; ++r) {
      int qp = qt * 16 + quad * 4 + r;
      U[qt][r] = qp * 64 + kl + ((qp & 7) << 3);
    }
#pragma unroll
  for (int tt = 0; tt < 4; ++tt) Wx[tt] = tt * 16 + hb8;

  bf16x8 vones;
#pragma unroll
  for (int j = 0; j < 8; ++j) vones[j] = (__bf16)1.0f;

  f32x4 oT[2][4] = {};   // [qt][nt], rows span dk
  f32x4 lacc[2] = {};    // row-sum per q (cols), all regs equal

#pragma unroll
  for (int i = 0; i < 2; ++i) {
    int l = wave * 128 + i * 64 + lane;
    int row = l >> 3, jg = (l & 7) ^ (row & 7);
    async_cp16(K + (size_t)row * DK_ + jg * 8, &Ks[0][(size_t)(l - lane) * 8]);
    async_cp16(V + (size_t)row * S_ + jg * 8, &Vs[0][(size_t)(l - lane) * 8]);
  }
  __syncthreads();

  for (int kb = 0; kb < S_; kb += 64) {
    const int cur = (kb >> 6) & 1;
    if (kb + 64 < S_) {
#pragma unroll
      for (int i = 0; i < 2; ++i) {
        int l = wave * 128 + i * 64 + lane;
        int row = l >> 3, jg = (l & 7) ^ (row & 7);
        async_cp16(K + (size_t)(kb + 64 + row) * DK_ + jg * 8,
                   &Ks[cur ^ 1][(size_t)(l - lane) * 8]);
        async_cp16(V + (size_t)row * S_ + (kb + 64) + jg * 8,
                   &Vs[cur ^ 1][(size_t)(l - lane) * 8]);
      }
    }

    const __bf16* ks = &Ks[cur][0];
    f32x4 s[2][4];
#pragma unroll
    for (int tt = 0; tt < 4; ++tt) {
      int row = tt * 16 + l15;
      bf16x8 kf0 = *(const bf16x8*)&ks[row * 64 + ((quad ^ (l15 & 7)) << 3)];
      bf16x8 kf1 = *(const bf16x8*)&ks[row * 64 + (((4 + quad) ^ (l15 & 7)) << 3)];
#pragma unroll
      for (int qt = 0; qt < 2; ++qt) {
        f32x4 z = {};
        z = __builtin_amdgcn_mfma_f32_16x16x32_bf16(qf[qt][0], kf0, z, 0, 0, 0);
        z = __builtin_amdgcn_mfma_f32_16x16x32_bf16(qf[qt][1], kf1, z, 0, 0, 0);
        s[qt][tt] = z;
      }
    }

#pragma unroll
    for (int tt = 0; tt < 4; ++tt) {
      const int mv = mk[kb + tt * 16 + l15];
#pragma unroll
      for (int qt = 0; qt < 2; ++qt) {
#pragma unroll
        for (int r = 0; r < 4; ++r) {
          float e = mv ? __builtin_exp2f(s[qt][tt][r]) : 0.f;
          P[wave][U[qt][r] ^ Wx[tt]] = (__bf16)e;
        }
      }
    }

    const __bf16* vs = &Vs[cur][0];
#pragma unroll
    for (int kt = 0; kt < 2; ++kt) {
      bf16x8 pf[2];
#pragma unroll
      for (int qt = 0; qt < 2; ++qt) {
        int qp = qt * 16 + l15;
        pf[qt] = *(const bf16x8*)&P[wave][qp * 64 +
                                          (((kt * 4 + quad) ^ (l15 & 7)) << 3)];
      }
#pragma unroll
      for (int qt = 0; qt < 2; ++qt)
        lacc[qt] = __builtin_amdgcn_mfma_f32_16x16x32_bf16(vones, pf[qt],
                                                           lacc[qt], 0, 0, 0);
#pragma unroll
      for (int nt = 0; nt < 4; ++nt) {
        int dk = nt * 16 + l15;
        bf16x8 vf = *(const bf16x8*)&vs[dk * 64 +
                                        (((kt * 4 + quad) ^ (l15 & 7)) << 3)];
#pragma unroll
        for (int qt = 0; qt < 2; ++qt)
          oT[qt][nt] = __builtin_amdgcn_mfma_f32_16x16x32_bf16(vf, pf[qt],
                                                               oT[qt][nt], 0, 0, 0);
      }
    }

    __syncthreads();
  }

#pragma unroll
  for (int qt = 0; qt < 2; ++qt) {
    float rinv = 1.0f / lacc[qt][0];
    int q = q0 + qt * 16 + l15;
#pragma unroll
    for (int nt = 0; nt < 4; ++nt) {
      bf16x4 pk;
#pragma unroll
      for (int r = 0; r < 4; ++r) pk[r] = (__bf16)(oT[qt][nt][r] * rinv);
      *(bf16x4*)&Out[(size_t)bh * S_ * DK_ + (size_t)q * DK_ + nt * 16 + quad * 4] = pk;
    }
  }
}

extern "C" void kernel_launch(void* const* d_in, const int* in_sizes, int n_in,
                              void* d_out, int out_size, void* d_ws, size_t ws_size,
                              hipStream_t stream) {
  const void* q = d_in[0];
  const void* k = d_in[1];
  const void* v = d_in[2];
  const int* mask = (const int*)d_in[3];
  const void* Wq = d_in[4];
  const void* Wk = d_in[5];
  const void* Wv = d_in[6];
  const void* Wo = d_in[7];

  const size_t NE = (size_t)B_ * H_ * S_ * DK_;  // 4,194,304 elems
  __bf16* Qh = (__bf16*)d_ws;                    // ws[0 : 8M)  -> becomes ctx
  __bf16* Kh = Qh + NE;                          // ws[8M : 16M)
  int* dflag = (int*)((char*)d_ws + 2 * NE * sizeof(__bf16));
  __bf16* Vt = (__bf16*)d_out;                   // scratch; dead before final write

  detect_dtype<<<1, 64, 0, stream>>>((const unsigned int*)q, dflag);
  dim3 g1(32, 8, 3);
  gemmk<128, 0><<<g1, 256, 0, stream>>>(q, k, v, Wq, Wk, Wv, Qh, Kh, Vt, dflag);
  attn<<<512, 256, 0, stream>>>(Qh, Kh, Vt, mask, Qh);
  dim3 g2(64, 8, 1);
  gemmk<64, 1><<<g2, 256, 0, stream>>>(Qh, Qh, Qh, Wo, Wo, Wo, d_out, d_out,
                                       d_out, dflag);
}

// Round 9
// 269.133 us; speedup vs baseline: 1.1030x; 1.1030x over previous
//
#include <hip/hip_runtime.h>

// MHA: B=2, S=2048, D=1024, H=16, DK=64. I/O bf16 (harness-confirmed R4);
// dual fp32 path retained via runtime detect. mask int32.
//
// Pipeline (ws 16 MB; d_out doubles as V scratch):
//   0) detect: classify d_in[0] bf16 vs fp32 -> flag in ws
//   1) gemmk<128,0>: Q/K/V proj y = x @ W^T (one launch, z selects tensor).
//        z=0: Qh [B,H,S,DK], pre-scaled by 0.125*log2e (softmax fold)
//        z=1: Kh [B,H,S,DK]
//        z=2: Vt [B,H,DK,S]  (transposed, bf16x4-packed stores)
//   2) attn (R8 form): flash, K/V LDS-staged (global_load_lds w16, dbuf,
//        XOR-swizzled), no-max exp2 softmax, XOR-factored P addresses,
//        row-sum via mfma(ones,P), swapped PV -> packed stores. ctx over Qh.
//   3) gemmk<64,1>: out = ctx @ Wo^T -> d_out (512 blocks).
//
// MFMA 16x16x32 bf16 layouts (verified):
//   A: lane holds A[m=lane&15][k=(lane>>4)*8+j]
//   B: lane holds B[k=(lane>>4)*8+j][n=lane&15]
//   C/D: col=lane&15, row=(lane>>4)*4+reg
//
// R4: no u16/bf16 punning (TBAA reorder -> NaN).
// R5: per-wave direct global K/V = latency bound -> LDS staging.
// R6: VGPR-roundtrip staging = latency bound -> global_load_lds w16.
// R7: attn de-VALU'd (XOR-factored P addrs, mfma row-sum) -> attn improved.
// R8 REGRESSION: runtime vt-branch inside gemm K-loop kept both MFMA
//   orientations live -> VGPR 84->108, occupancy 28->15%, +20us. Reverted to
//   single orientation (vt only in epilogue). BK 32->64: halves barrier
//   count per MFMA (barrier-drain bound kernel), 32KB LDS.

typedef __bf16 bf16x8 __attribute__((ext_vector_type(8)));
typedef __bf16 bf16x4 __attribute__((ext_vector_type(4)));
typedef float f32x4 __attribute__((ext_vector_type(4)));

#define B_ 2
#define S_ 2048
#define D_ 1024
#define H_ 16
#define DK_ 64
#define QSCALE 0.18033688011112042f  // 0.125 * log2(e)

// ---------------------------------------------------------------------------
__global__ void detect_dtype(const unsigned int* __restrict__ qw,
                             int* __restrict__ flag) {
  int cnt = 0;
#pragma unroll
  for (int i = 0; i < 4; ++i) {
    unsigned int w = qw[threadIdx.x + 64 * i];
    int e = (w >> 7) & 0xFF;
    cnt += (e >= 100 && e <= 140) ? 1 : 0;
  }
#pragma unroll
  for (int off = 32; off > 0; off >>= 1) cnt += __shfl_down(cnt, off, 64);
  if (threadIdx.x == 0) *flag = (cnt >= 128) ? 0 : 1;
}

__device__ __forceinline__ bf16x8 load8cvt(const void* base, size_t eoff,
                                           bool f32) {
  if (!f32) return *(const bf16x8*)((const __bf16*)base + eoff);
  const float* p = (const float*)base + eoff;
  bf16x8 r;
#pragma unroll
  for (int j = 0; j < 8; ++j) r[j] = (__bf16)p[j];
  return r;
}

// async 16B global -> LDS (lds dest = wave-uniform base + lane*16)
__device__ __forceinline__ void async_cp16(const __bf16* g, __bf16* l) {
  __builtin_amdgcn_global_load_lds(
      (const __attribute__((address_space(1))) unsigned int*)g,
      (__attribute__((address_space(3))) unsigned int*)l, 16, 0, 0);
}

// ---------------------------------------------------------------------------
// GEMM: C[M,N] = X[M,K] @ W[N,K]^T, M=4096, N=K=1024, TM x 128 tile, BK=64.
// LDS unpadded [rows][64]; 16B chunks XOR-swizzled: phys chunk j at row r
// holds logical chunk j ^ (r&7) (same scheme as attn Ks, 0 conflicts).
// Staging via global_load_lds w16 (bf16) / load+convert (fp32 fallback).
// Single MFMA orientation mfma(af, bfr); vt handled only in the epilogue.
// TM=128: 4 waves 2x2 of 64x64 (32 MFMA/wave/iter). TM=64: 1x4 of 64x32.
// MODE 0: X external row-major; O bf16 per-z layout (see pipeline above).
// MODE 1: X internal bf16 head-split [B,H,S,DK]; O external row-major.
// ---------------------------------------------------------------------------
template <int TM, int MODE>
__global__ __launch_bounds__(256) void gemmk(
    const void* X0, const void* X1, const void* X2,
    const void* W0, const void* W1, const void* W2,
    void* O0, void* O1, void* O2, const int* __restrict__ dflag) {
  constexpr int Kd = 1024, Nd = 1024;
  constexpr int NI = (TM == 128) ? 4 : 2;   // n 16-tiles per wave
  constexpr int ACH = TM / 32;              // A async wave-loads per wave/iter
  constexpr int BCH = 4;                    // B async wave-loads per wave/iter
  const void* X = (blockIdx.z == 0) ? X0 : (blockIdx.z == 1 ? X1 : X2);
  const void* W = (blockIdx.z == 0) ? W0 : (blockIdx.z == 1 ? W1 : W2);
  void* O = (blockIdx.z == 0) ? O0 : (blockIdx.z == 1 ? O1 : O2);
  const bool f32io = (*dflag != 0);

  __shared__ __attribute__((aligned(16))) __bf16 As[TM * 64];
  __shared__ __attribute__((aligned(16))) __bf16 Bs[128 * 64];

  const int m0 = blockIdx.x * TM;
  const int n0 = blockIdx.y * 128;
  const int t = threadIdx.x;
  const int lane = t & 63, wave = t >> 6;
  const int l15 = lane & 15, quad = lane >> 4;
  const int wm = (TM == 128) ? (wave >> 1) * 64 : 0;
  const int wn = (TM == 128) ? (wave & 1) * 64 : wave * 32;

  // ---- per-lane staging addresses (bf16 fast path) ----
  const __bf16* gA[ACH];
  __bf16* ldsA[ACH];
#pragma unroll
  for (int i = 0; i < ACH; ++i) {
    int c = (wave * ACH + i) * 64 + lane;   // phys chunk id
    int row = c >> 3, j = c & 7;
    int jl = j ^ (row & 7);                 // logical chunk
    ldsA[i] = &As[(wave * ACH + i) * 512];  // wave-uniform base
    if (MODE == 0) {
      gA[i] = (const __bf16*)X + (size_t)(m0 + row) * Kd + jl * 8;
    } else {
      int gm = m0 + row;
      gA[i] = (const __bf16*)X + (size_t)(gm >> 11) * (H_ * S_ * DK_) +
              (size_t)(gm & (S_ - 1)) * DK_ + jl * 8;
      // + (k0>>6)*S_*DK_ per iter (jl*8 < 64 stays within one head)
    }
  }
  const __bf16* gB[BCH];
  __bf16* ldsB[BCH];
#pragma unroll
  for (int i = 0; i < BCH; ++i) {
    int c = (wave * BCH + i) * 64 + lane;
    int row = c >> 3, j = c & 7;
    int jl = j ^ (row & 7);
    ldsB[i] = &Bs[(wave * BCH + i) * 512];
    gB[i] = (const __bf16*)W + (size_t)(n0 + row) * Kd + jl * 8;
  }

  f32x4 acc[4][NI] = {};

  for (int k0 = 0; k0 < Kd; k0 += 64) {
    __syncthreads();  // prev iter's frag reads complete before overwrite
    if (!f32io) {
      if (MODE == 0) {
#pragma unroll
        for (int i = 0; i < ACH; ++i) async_cp16(gA[i] + k0, ldsA[i]);
      } else {
        const size_t koff = (size_t)(k0 >> 6) * (S_ * DK_);
#pragma unroll
        for (int i = 0; i < ACH; ++i) async_cp16(gA[i] + koff, ldsA[i]);
      }
#pragma unroll
      for (int i = 0; i < BCH; ++i) async_cp16(gB[i] + k0, ldsB[i]);
    } else {
      // fp32 fallback: load + convert + swizzled LDS store
#pragma unroll
      for (int i = 0; i < TM / 32; ++i) {
        int c = t + 256 * i;
        int row = c >> 3, j = c & 7;
        int jl = j ^ (row & 7);
        bf16x8 xv;
        if (MODE == 0) {
          xv = load8cvt(X, (size_t)(m0 + row) * Kd + k0 + jl * 8, true);
        } else {
          int gm = m0 + row, gk = k0 + jl * 8;
          xv = *(const bf16x8*)((const __bf16*)X +
                ((((size_t)(gm >> 11) * H_ + (gk >> 6)) * S_) +
                 (gm & (S_ - 1))) * DK_ + (gk & (DK_ - 1)));
        }
        *(bf16x8*)&As[row * 64 + j * 8] = xv;
      }
#pragma unroll
      for (int i = 0; i < 4; ++i) {
        int c = t + 256 * i;
        int row = c >> 3, j = c & 7;
        int jl = j ^ (row & 7);
        bf16x8 wv = load8cvt(W, (size_t)(n0 + row) * Kd + k0 + jl * 8, true);
        *(bf16x8*)&Bs[row * 64 + j * 8] = wv;
      }
    }
    __syncthreads();  // staging visible (implies vmcnt drain)

#pragma unroll
    for (int h = 0; h < 2; ++h) {  // two K=32 sub-steps per LDS tile
      bf16x8 af[4], bfr[NI];
#pragma unroll
      for (int mi = 0; mi < 4; ++mi) {
        int row = wm + mi * 16 + l15;
        af[mi] = *(const bf16x8*)&As[row * 64 +
                                     (((h * 4 + quad) ^ (row & 7)) << 3)];
      }
#pragma unroll
      for (int ni = 0; ni < NI; ++ni) {
        int row = wn + ni * 16 + l15;
        bfr[ni] = *(const bf16x8*)&Bs[row * 64 +
                                      (((h * 4 + quad) ^ (row & 7)) << 3)];
      }
#pragma unroll
      for (int mi = 0; mi < 4; ++mi)
#pragma unroll
        for (int ni = 0; ni < NI; ++ni)
          acc[mi][ni] = __builtin_amdgcn_mfma_f32_16x16x32_bf16(
              af[mi], bfr[ni], acc[mi][ni], 0, 0, 0);
    }
  }

  // ---- epilogue (R7-proven form: vt only here) ----
  const float oscale = (MODE == 0 && blockIdx.z == 0) ? QSCALE : 1.0f;
#pragma unroll
  for (int mi = 0; mi < 4; ++mi) {
#pragma unroll
    for (int ni = 0; ni < NI; ++ni) {
      int mbase = m0 + wm + mi * 16 + quad * 4;
      int n = n0 + wn + ni * 16 + l15;
      if (MODE == 0 && blockIdx.z == 2) {
        // Vt [B,H,DK,S]: dk fixed per lane, s consecutive in r -> 8B store
        int b = mbase >> 11, sb = mbase & (S_ - 1);
        int h = n >> 6, dk = n & (DK_ - 1);
        bf16x4 pk;
#pragma unroll
        for (int r = 0; r < 4; ++r) pk[r] = (__bf16)acc[mi][ni][r];
        *(bf16x4*)&((__bf16*)O)[((size_t)(b * H_ + h) * DK_ + dk) * S_ + sb] = pk;
      } else {
#pragma unroll
        for (int r = 0; r < 4; ++r) {
          int m = mbase + r;
          float val = acc[mi][ni][r] * oscale;
          if (MODE == 0) {
            int b = m >> 11, s = m & (S_ - 1);
            int h = n >> 6, dk = n & (DK_ - 1);
            ((__bf16*)O)[((size_t)(b * H_ + h) * S_ + s) * DK_ + dk] = (__bf16)val;
          } else {
            size_t idx = (size_t)m * Nd + n;
            if (f32io) ((float*)O)[idx] = val;
            else       ((__bf16*)O)[idx] = (__bf16)val;
          }
        }
      }
    }
  }
}

// ---------------------------------------------------------------------------
// Flash attention (R8 form, unchanged). Block = (b,h) x 128 q-rows, 4 waves x
// 32 q-rows, 64 keys/iter, K/V double-buffered via global_load_lds w16,
// XOR-swizzled. P addrs factored addr = U[qt][r] ^ Wx[tt]. Row-sum via
// mfma(ones, pf). PV swapped (mfma(vf, pf)) -> packed bf16x4 stores.
// ---------------------------------------------------------------------------
__global__ __launch_bounds__(256) void attn(
    const __bf16* Qh, const __bf16* __restrict__ Kh,
    const __bf16* __restrict__ Vt, const int* __restrict__ mask,
    __bf16* Out) {
  __shared__ __attribute__((aligned(16))) __bf16 Ks[2][4096];
  __shared__ __attribute__((aligned(16))) __bf16 Vs[2][4096];
  __shared__ __attribute__((aligned(16))) __bf16 P[4][2048];

  const int t = threadIdx.x;
  const int lane = t & 63, wave = t >> 6;
  const int l15 = lane & 15, quad = lane >> 4;
  const int qb = blockIdx.x & 15;   // 16 q-blocks of 128
  const int bh = blockIdx.x >> 4;   // b*H + h
  const int b = bh >> 4;
  const int q0 = qb * 128 + wave * 32;

  const __bf16* Q = Qh + (size_t)bh * S_ * DK_;
  const __bf16* K = Kh + (size_t)bh * S_ * DK_;
  const __bf16* V = Vt + (size_t)bh * DK_ * S_;   // [dk][s]
  const int* mk = mask + b * S_;

  bf16x8 qf[2][2];
#pragma unroll
  for (int qt = 0; qt < 2; ++qt)
#pragma unroll
    for (int h = 0; h < 2; ++h)
      qf[qt][h] = *(const bf16x8*)&Q[(size_t)(q0 + qt * 16 + l15) * DK_ +
                                     h * 32 + quad * 8];

  const int kl = l15 & 7, hb8 = l15 & 8;
  int U[2][4], Wx[4];
#pragma unroll
  for (int qt = 0; qt < 2; ++qt)
#pragma unroll
    for (int r = 0; r < 4; ++r) {
      int qp = qt * 16 + quad * 4 + r;
      U[qt][r] = qp * 64 + kl + ((qp & 7) << 3);
    }
#pragma unroll
  for (int tt = 0; tt < 4; ++tt) Wx[tt] = tt * 16 + hb8;

  bf16x8 vones;
#pragma unroll
  for (int j = 0; j < 8; ++j) vones[j] = (__bf16)1.0f;

  f32x4 oT[2][4] = {};   // [qt][nt], rows span dk
  f32x4 lacc[2] = {};    // row-sum per q

#pragma unroll
  for (int i = 0; i < 2; ++i) {
    int l = wave * 128 + i * 64 + lane;
    int row = l >> 3, jg = (l & 7) ^ (row & 7);
    async_cp16(K + (size_t)row * DK_ + jg * 8, &Ks[0][(size_t)(l - lane) * 8]);
    async_cp16(V + (size_t)row * S_ + jg * 8, &Vs[0][(size_t)(l - lane) * 8]);
  }
  __syncthreads();

  for (int kb = 0; kb < S_; kb += 64) {
    const int cur = (kb >> 6) & 1;
    if (kb + 64 < S_) {
#pragma unroll
      for (int i = 0; i < 2; ++i) {
        int l = wave * 128 + i * 64 + lane;
        int row = l >> 3, jg = (l & 7) ^ (row & 7);
        async_cp16(K + (size_t)(kb + 64 + row) * DK_ + jg * 8,
                   &Ks[cur ^ 1][(size_t)(l - lane) * 8]);
        async_cp16(V + (size_t)row * S_ + (kb + 64) + jg * 8,
                   &Vs[cur ^ 1][(size_t)(l - lane) * 8]);
      }
    }

    const __bf16* ks = &Ks[cur][0];
    f32x4 s[2][4];
#pragma unroll
    for (int tt = 0; tt < 4; ++tt) {
      int row = tt * 16 + l15;
      bf16x8 kf0 = *(const bf16x8*)&ks[row * 64 + ((quad ^ (l15 & 7)) << 3)];
      bf16x8 kf1 = *(const bf16x8*)&ks[row * 64 + (((4 + quad) ^ (l15 & 7)) << 3)];
#pragma unroll
      for (int qt = 0; qt < 2; ++qt) {
        f32x4 z = {};
        z = __builtin_amdgcn_mfma_f32_16x16x32_bf16(qf[qt][0], kf0, z, 0, 0, 0);
        z = __builtin_amdgcn_mfma_f32_16x16x32_bf16(qf[qt][1], kf1, z, 0, 0, 0);
        s[qt][tt] = z;
      }
    }

#pragma unroll
    for (int tt = 0; tt < 4; ++tt) {
      const int mv = mk[kb + tt * 16 + l15];
#pragma unroll
      for (int qt = 0; qt < 2; ++qt) {
#pragma unroll
        for (int r = 0; r < 4; ++r) {
          float e = mv ? __builtin_exp2f(s[qt][tt][r]) : 0.f;
          P[wave][U[qt][r] ^ Wx[tt]] = (__bf16)e;
        }
      }
    }

    const __bf16* vs = &Vs[cur][0];
#pragma unroll
    for (int kt = 0; kt < 2; ++kt) {
      bf16x8 pf[2];
#pragma unroll
      for (int qt = 0; qt < 2; ++qt) {
        int qp = qt * 16 + l15;
        pf[qt] = *(const bf16x8*)&P[wave][qp * 64 +
                                          (((kt * 4 + quad) ^ (l15 & 7)) << 3)];
      }
#pragma unroll
      for (int qt = 0; qt < 2; ++qt)
        lacc[qt] = __builtin_amdgcn_mfma_f32_16x16x32_bf16(vones, pf[qt],
                                                           lacc[qt], 0, 0, 0);
#pragma unroll
      for (int nt = 0; nt < 4; ++nt) {
        int dk = nt * 16 + l15;
        bf16x8 vf = *(const bf16x8*)&vs[dk * 64 +
                                        (((kt * 4 + quad) ^ (l15 & 7)) << 3)];
#pragma unroll
        for (int qt = 0; qt < 2; ++qt)
          oT[qt][nt] = __builtin_amdgcn_mfma_f32_16x16x32_bf16(vf, pf[qt],
                                                               oT[qt][nt], 0, 0, 0);
      }
    }

    __syncthreads();
  }

#pragma unroll
  for (int qt = 0; qt < 2; ++qt) {
    float rinv = 1.0f / lacc[qt][0];
    int q = q0 + qt * 16 + l15;
#pragma unroll
    for (int nt = 0; nt < 4; ++nt) {
      bf16x4 pk;
#pragma unroll
      for (int r = 0; r < 4; ++r) pk[r] = (__bf16)(oT[qt][nt][r] * rinv);
      *(bf16x4*)&Out[(size_t)bh * S_ * DK_ + (size_t)q * DK_ + nt * 16 + quad * 4] = pk;
    }
  }
}

extern "C" void kernel_launch(void* const* d_in, const int* in_sizes, int n_in,
                              void* d_out, int out_size, void* d_ws, size_t ws_size,
                              hipStream_t stream) {
  const void* q = d_in[0];
  const void* k = d_in[1];
  const void* v = d_in[2];
  const int* mask = (const int*)d_in[3];
  const void* Wq = d_in[4];
  const void* Wk = d_in[5];
  const void* Wv = d_in[6];
  const void* Wo = d_in[7];

  const size_t NE = (size_t)B_ * H_ * S_ * DK_;  // 4,194,304 elems
  __bf16* Qh = (__bf16*)d_ws;                    // ws[0 : 8M)  -> becomes ctx
  __bf16* Kh = Qh + NE;                          // ws[8M : 16M)
  int* dflag = (int*)((char*)d_ws + 2 * NE * sizeof(__bf16));
  __bf16* Vt = (__bf16*)d_out;                   // scratch; dead before final write

  detect_dtype<<<1, 64, 0, stream>>>((const unsigned int*)q, dflag);
  dim3 g1(32, 8, 3);
  gemmk<128, 0><<<g1, 256, 0, stream>>>(q, k, v, Wq, Wk, Wv, Qh, Kh, Vt, dflag);
  attn<<<512, 256, 0, stream>>>(Qh, Kh, Vt, mask, Qh);
  dim3 g2(64, 8, 1);
  gemmk<64, 1><<<g2, 256, 0, stream>>>(Qh, Qh, Qh, Wo, Wo, Wo, d_out, d_out,
                                       d_out, dflag);
}

// Round 10
// 263.221 us; speedup vs baseline: 1.1278x; 1.0225x over previous
//
#include <hip/hip_runtime.h>

// MHA: B=2, S=2048, D=1024, H=16, DK=64. I/O bf16 (harness-confirmed R4);
// dual fp32 path retained via runtime detect. mask int32.
//
// Pipeline (ws 16 MB; d_out doubles as V scratch):
//   0) detect: classify d_in[0] bf16 vs fp32 -> flag in ws
//   1) gemmk<128,0>: Q/K/V proj y = x @ W^T (one launch, z selects tensor).
//        z=0: Qh [B,H,S,DK], pre-scaled by 0.125*log2e (softmax fold)
//        z=1: Kh [B,H,S,DK]
//        z=2: Vt [B,H,DK,S]  (transposed, bf16x4-packed stores)
//   2) attn: flash, R7-form inner loop, 64 q-rows/block (16/wave), 64
//        keys/iter, K/V LDS dbuf via global_load_lds w16 (XOR-swizzled),
//        mask folded into score-accumulator init, no-max exp2 softmax,
//        P round-trip wave-private LDS. ctx IN PLACE over Qh. grid 1024.
//   3) gemmk<64,1>: out = ctx @ Wo^T -> d_out (512 blocks).
//
// MFMA 16x16x32 bf16 layouts (verified):
//   A: lane holds A[m=lane&15][k=(lane>>4)*8+j]
//   B: lane holds B[k=(lane>>4)*8+j][n=lane&15]
//   C/D: col=lane&15, row=(lane>>4)*4+reg
//
// R4: no u16/bf16 punning (TBAA reorder -> NaN).
// R5: per-wave direct global K/V = latency bound -> LDS staging.
// R6: VGPR-roundtrip staging = latency bound -> global_load_lds w16.
// R8 REGRESSION: dual MFMA orientation in gemm K-loop (VGPR 84->108).
// R9 lessons: BK=64 gemms WIN (kept verbatim). R8-form attn (lacc-mfma
//   rowsum + xor-factored addrs) REGRESSED vs R7-form (94.4 vs 83.4 us,
//   same VALU%): compiler already CSE'd addr math; lacc lengthened the pf
//   chain. attn is VALU-issue bound at 2 blocks/CU -> this round: R7-form
//   inner + 64q/block (4 blocks/CU TLP) + mask-as-accinit.

typedef __bf16 bf16x8 __attribute__((ext_vector_type(8)));
typedef __bf16 bf16x4 __attribute__((ext_vector_type(4)));
typedef float f32x4 __attribute__((ext_vector_type(4)));

#define B_ 2
#define S_ 2048
#define D_ 1024
#define H_ 16
#define DK_ 64
#define QSCALE 0.18033688011112042f  // 0.125 * log2(e)

// ---------------------------------------------------------------------------
__global__ void detect_dtype(const unsigned int* __restrict__ qw,
                             int* __restrict__ flag) {
  int cnt = 0;
#pragma unroll
  for (int i = 0; i < 4; ++i) {
    unsigned int w = qw[threadIdx.x + 64 * i];
    int e = (w >> 7) & 0xFF;
    cnt += (e >= 100 && e <= 140) ? 1 : 0;
  }
#pragma unroll
  for (int off = 32; off > 0; off >>= 1) cnt += __shfl_down(cnt, off, 64);
  if (threadIdx.x == 0) *flag = (cnt >= 128) ? 0 : 1;
}

__device__ __forceinline__ bf16x8 load8cvt(const void* base, size_t eoff,
                                           bool f32) {
  if (!f32) return *(const bf16x8*)((const __bf16*)base + eoff);
  const float* p = (const float*)base + eoff;
  bf16x8 r;
#pragma unroll
  for (int j = 0; j < 8; ++j) r[j] = (__bf16)p[j];
  return r;
}

// async 16B global -> LDS (lds dest = wave-uniform base + lane*16)
__device__ __forceinline__ void async_cp16(const __bf16* g, __bf16* l) {
  __builtin_amdgcn_global_load_lds(
      (const __attribute__((address_space(1))) unsigned int*)g,
      (__attribute__((address_space(3))) unsigned int*)l, 16, 0, 0);
}

// ---------------------------------------------------------------------------
// GEMM (R9 verbatim): C[M,N] = X[M,K] @ W[N,K]^T, TM x 128 tile, BK=64.
// LDS unpadded [rows][64]; 16B chunks XOR-swizzled (phys j = jl ^ (row&7)).
// Staging via global_load_lds w16 (bf16) / load+convert (fp32 fallback).
// Single MFMA orientation; vt handled only in the epilogue.
// ---------------------------------------------------------------------------
template <int TM, int MODE>
__global__ __launch_bounds__(256) void gemmk(
    const void* X0, const void* X1, const void* X2,
    const void* W0, const void* W1, const void* W2,
    void* O0, void* O1, void* O2, const int* __restrict__ dflag) {
  constexpr int Kd = 1024, Nd = 1024;
  constexpr int NI = (TM == 128) ? 4 : 2;
  constexpr int ACH = TM / 32;
  constexpr int BCH = 4;
  const void* X = (blockIdx.z == 0) ? X0 : (blockIdx.z == 1 ? X1 : X2);
  const void* W = (blockIdx.z == 0) ? W0 : (blockIdx.z == 1 ? W1 : W2);
  void* O = (blockIdx.z == 0) ? O0 : (blockIdx.z == 1 ? O1 : O2);
  const bool f32io = (*dflag != 0);

  __shared__ __attribute__((aligned(16))) __bf16 As[TM * 64];
  __shared__ __attribute__((aligned(16))) __bf16 Bs[128 * 64];

  const int m0 = blockIdx.x * TM;
  const int n0 = blockIdx.y * 128;
  const int t = threadIdx.x;
  const int lane = t & 63, wave = t >> 6;
  const int l15 = lane & 15, quad = lane >> 4;
  const int wm = (TM == 128) ? (wave >> 1) * 64 : 0;
  const int wn = (TM == 128) ? (wave & 1) * 64 : wave * 32;

  const __bf16* gA[ACH];
  __bf16* ldsA[ACH];
#pragma unroll
  for (int i = 0; i < ACH; ++i) {
    int c = (wave * ACH + i) * 64 + lane;
    int row = c >> 3, j = c & 7;
    int jl = j ^ (row & 7);
    ldsA[i] = &As[(wave * ACH + i) * 512];
    if (MODE == 0) {
      gA[i] = (const __bf16*)X + (size_t)(m0 + row) * Kd + jl * 8;
    } else {
      int gm = m0 + row;
      gA[i] = (const __bf16*)X + (size_t)(gm >> 11) * (H_ * S_ * DK_) +
              (size_t)(gm & (S_ - 1)) * DK_ + jl * 8;
    }
  }
  const __bf16* gB[BCH];
  __bf16* ldsB[BCH];
#pragma unroll
  for (int i = 0; i < BCH; ++i) {
    int c = (wave * BCH + i) * 64 + lane;
    int row = c >> 3, j = c & 7;
    int jl = j ^ (row & 7);
    ldsB[i] = &Bs[(wave * BCH + i) * 512];
    gB[i] = (const __bf16*)W + (size_t)(n0 + row) * Kd + jl * 8;
  }

  f32x4 acc[4][NI] = {};

  for (int k0 = 0; k0 < Kd; k0 += 64) {
    __syncthreads();
    if (!f32io) {
      if (MODE == 0) {
#pragma unroll
        for (int i = 0; i < ACH; ++i) async_cp16(gA[i] + k0, ldsA[i]);
      } else {
        const size_t koff = (size_t)(k0 >> 6) * (S_ * DK_);
#pragma unroll
        for (int i = 0; i < ACH; ++i) async_cp16(gA[i] + koff, ldsA[i]);
      }
#pragma unroll
      for (int i = 0; i < BCH; ++i) async_cp16(gB[i] + k0, ldsB[i]);
    } else {
#pragma unroll
      for (int i = 0; i < TM / 32; ++i) {
        int c = t + 256 * i;
        int row = c >> 3, j = c & 7;
        int jl = j ^ (row & 7);
        bf16x8 xv;
        if (MODE == 0) {
          xv = load8cvt(X, (size_t)(m0 + row) * Kd + k0 + jl * 8, true);
        } else {
          int gm = m0 + row, gk = k0 + jl * 8;
          xv = *(const bf16x8*)((const __bf16*)X +
                ((((size_t)(gm >> 11) * H_ + (gk >> 6)) * S_) +
                 (gm & (S_ - 1))) * DK_ + (gk & (DK_ - 1)));
        }
        *(bf16x8*)&As[row * 64 + j * 8] = xv;
      }
#pragma unroll
      for (int i = 0; i < 4; ++i) {
        int c = t + 256 * i;
        int row = c >> 3, j = c & 7;
        int jl = j ^ (row & 7);
        bf16x8 wv = load8cvt(W, (size_t)(n0 + row) * Kd + k0 + jl * 8, true);
        *(bf16x8*)&Bs[row * 64 + j * 8] = wv;
      }
    }
    __syncthreads();

#pragma unroll
    for (int h = 0; h < 2; ++h) {
      bf16x8 af[4], bfr[NI];
#pragma unroll
      for (int mi = 0; mi < 4; ++mi) {
        int row = wm + mi * 16 + l15;
        af[mi] = *(const bf16x8*)&As[row * 64 +
                                     (((h * 4 + quad) ^ (row & 7)) << 3)];
      }
#pragma unroll
      for (int ni = 0; ni < NI; ++ni) {
        int row = wn + ni * 16 + l15;
        bfr[ni] = *(const bf16x8*)&Bs[row * 64 +
                                      (((h * 4 + quad) ^ (row & 7)) << 3)];
      }
#pragma unroll
      for (int mi = 0; mi < 4; ++mi)
#pragma unroll
        for (int ni = 0; ni < NI; ++ni)
          acc[mi][ni] = __builtin_amdgcn_mfma_f32_16x16x32_bf16(
              af[mi], bfr[ni], acc[mi][ni], 0, 0, 0);
    }
  }

  const float oscale = (MODE == 0 && blockIdx.z == 0) ? QSCALE : 1.0f;
#pragma unroll
  for (int mi = 0; mi < 4; ++mi) {
#pragma unroll
    for (int ni = 0; ni < NI; ++ni) {
      int mbase = m0 + wm + mi * 16 + quad * 4;
      int n = n0 + wn + ni * 16 + l15;
      if (MODE == 0 && blockIdx.z == 2) {
        int b = mbase >> 11, sb = mbase & (S_ - 1);
        int h = n >> 6, dk = n & (DK_ - 1);
        bf16x4 pk;
#pragma unroll
        for (int r = 0; r < 4; ++r) pk[r] = (__bf16)acc[mi][ni][r];
        *(bf16x4*)&((__bf16*)O)[((size_t)(b * H_ + h) * DK_ + dk) * S_ + sb] = pk;
      } else {
#pragma unroll
        for (int r = 0; r < 4; ++r) {
          int m = mbase + r;
          float val = acc[mi][ni][r] * oscale;
          if (MODE == 0) {
            int b = m >> 11, s = m & (S_ - 1);
            int h = n >> 6, dk = n & (DK_ - 1);
            ((__bf16*)O)[((size_t)(b * H_ + h) * S_ + s) * DK_ + dk] = (__bf16)val;
          } else {
            size_t idx = (size_t)m * Nd + n;
            if (f32io) ((float*)O)[idx] = val;
            else       ((__bf16*)O)[idx] = (__bf16)val;
          }
        }
      }
    }
  }
}

// ---------------------------------------------------------------------------
// Flash attention, R7-form inner loop, 64 q-rows/block (16/wave), 64
// keys/iter. grid 1024 -> 4 blocks/CU (LDS 40KB). Mask folded into the
// score-accumulator init (z = 0 or -1e9 per key lane -> exp2 underflows to
// 0 for masked keys; softmax shift-equivalent to the reference's where()).
// P round-trip through wave-private swizzled LDS (no barriers needed).
// ---------------------------------------------------------------------------
__global__ __launch_bounds__(256) void attn(
    const __bf16* Qh, const __bf16* __restrict__ Kh,
    const __bf16* __restrict__ Vt, const int* __restrict__ mask,
    __bf16* Out) {
  __shared__ __attribute__((aligned(16))) __bf16 Ks[2][4096];
  __shared__ __attribute__((aligned(16))) __bf16 Vs[2][4096];
  __shared__ __attribute__((aligned(16))) __bf16 P[4][1024];

  const int t = threadIdx.x;
  const int lane = t & 63, wave = t >> 6;
  const int l15 = lane & 15, quad = lane >> 4;
  const int qb = blockIdx.x & 31;   // 32 q-blocks of 64
  const int bh = blockIdx.x >> 5;   // b*H + h
  const int b = bh >> 4;
  const int q0 = qb * 64 + wave * 16;

  const __bf16* Q = Qh + (size_t)bh * S_ * DK_;
  const __bf16* K = Kh + (size_t)bh * S_ * DK_;
  const __bf16* V = Vt + (size_t)bh * DK_ * S_;   // [dk][s]
  const int* mk = mask + b * S_;

  bf16x8 qf0 = *(const bf16x8*)&Q[(size_t)(q0 + l15) * DK_ + quad * 8];
  bf16x8 qf1 = *(const bf16x8*)&Q[(size_t)(q0 + l15) * DK_ + 32 + quad * 8];

  f32x4 o[4] = {};
  float lsum[4] = {};

  // prologue: stage tile 0 into buf 0
#pragma unroll
  for (int i = 0; i < 2; ++i) {
    int l = wave * 128 + i * 64 + lane;
    int row = l >> 3, jg = (l & 7) ^ (row & 7);
    async_cp16(K + (size_t)row * DK_ + jg * 8, &Ks[0][(size_t)(l - lane) * 8]);
    async_cp16(V + (size_t)row * S_ + jg * 8, &Vs[0][(size_t)(l - lane) * 8]);
  }
  __syncthreads();

  for (int kb = 0; kb < S_; kb += 64) {
    const int cur = (kb >> 6) & 1;
    if (kb + 64 < S_) {
#pragma unroll
      for (int i = 0; i < 2; ++i) {
        int l = wave * 128 + i * 64 + lane;
        int row = l >> 3, jg = (l & 7) ^ (row & 7);
        async_cp16(K + (size_t)(kb + 64 + row) * DK_ + jg * 8,
                   &Ks[cur ^ 1][(size_t)(l - lane) * 8]);
        async_cp16(V + (size_t)row * S_ + (kb + 64) + jg * 8,
                   &Vs[cur ^ 1][(size_t)(l - lane) * 8]);
      }
    }

    // ---- scores: 64 keys x 16 q-rows; mask enters via acc init ----
    const __bf16* ks = &Ks[cur][0];
    f32x4 s[4];
#pragma unroll
    for (int tt = 0; tt < 4; ++tt) {
      int row = tt * 16 + l15;
      bf16x8 kf0 = *(const bf16x8*)&ks[row * 64 + ((quad ^ (l15 & 7)) << 3)];
      bf16x8 kf1 = *(const bf16x8*)&ks[row * 64 + (((4 + quad) ^ (l15 & 7)) << 3)];
      float bias = mk[kb + tt * 16 + l15] ? 0.f : -1e9f;
      f32x4 z = {bias, bias, bias, bias};
      z = __builtin_amdgcn_mfma_f32_16x16x32_bf16(qf0, kf0, z, 0, 0, 0);
      z = __builtin_amdgcn_mfma_f32_16x16x32_bf16(qf1, kf1, z, 0, 0, 0);
      s[tt] = z;
    }

    // ---- exp2 + P store (wave-private, swizzled) ----
#pragma unroll
    for (int tt = 0; tt < 4; ++tt) {
      const int jbase = tt * 2 + (l15 >> 3);
      const int kl = l15 & 7;
#pragma unroll
      for (int r = 0; r < 4; ++r) {
        float e = __builtin_exp2f(s[tt][r]);   // Q carries 0.125*log2e
        lsum[r] += e;
        int qp = quad * 4 + r;
        P[wave][qp * 64 + ((jbase ^ (qp & 7)) << 3) + kl] = (__bf16)e;
      }
    }

    // ---- PV ----
    const __bf16* vs = &Vs[cur][0];
#pragma unroll
    for (int kt = 0; kt < 2; ++kt) {
      bf16x8 pf = *(const bf16x8*)&P[wave][l15 * 64 +
                                           (((kt * 4 + quad) ^ (l15 & 7)) << 3)];
#pragma unroll
      for (int nt = 0; nt < 4; ++nt) {
        int dk = nt * 16 + l15;
        bf16x8 vf = *(const bf16x8*)&vs[dk * 64 +
                                        (((kt * 4 + quad) ^ (l15 & 7)) << 3)];
        o[nt] = __builtin_amdgcn_mfma_f32_16x16x32_bf16(pf, vf, o[nt], 0, 0, 0);
      }
    }

    __syncthreads();  // drains staging vmcnt; separates buffer reuse
  }

  float rinv[4];
#pragma unroll
  for (int r = 0; r < 4; ++r) {
    float v = lsum[r];
#pragma unroll
    for (int off = 8; off > 0; off >>= 1) v += __shfl_xor(v, off, 16);
    rinv[r] = 1.0f / v;
  }

#pragma unroll
  for (int nt = 0; nt < 4; ++nt) {
#pragma unroll
    for (int r = 0; r < 4; ++r) {
      int qrow = q0 + quad * 4 + r;
      Out[(size_t)bh * S_ * DK_ + (size_t)qrow * DK_ + nt * 16 + l15] =
          (__bf16)(o[nt][r] * rinv[r]);
    }
  }
}

extern "C" void kernel_launch(void* const* d_in, const int* in_sizes, int n_in,
                              void* d_out, int out_size, void* d_ws, size_t ws_size,
                              hipStream_t stream) {
  const void* q = d_in[0];
  const void* k = d_in[1];
  const void* v = d_in[2];
  const int* mask = (const int*)d_in[3];
  const void* Wq = d_in[4];
  const void* Wk = d_in[5];
  const void* Wv = d_in[6];
  const void* Wo = d_in[7];

  const size_t NE = (size_t)B_ * H_ * S_ * DK_;  // 4,194,304 elems
  __bf16* Qh = (__bf16*)d_ws;                    // ws[0 : 8M)  -> becomes ctx
  __bf16* Kh = Qh + NE;                          // ws[8M : 16M)
  int* dflag = (int*)((char*)d_ws + 2 * NE * sizeof(__bf16));
  __bf16* Vt = (__bf16*)d_out;                   // scratch; dead before final write

  detect_dtype<<<1, 64, 0, stream>>>((const unsigned int*)q, dflag);
  dim3 g1(32, 8, 3);
  gemmk<128, 0><<<g1, 256, 0, stream>>>(q, k, v, Wq, Wk, Wv, Qh, Kh, Vt, dflag);
  attn<<<1024, 256, 0, stream>>>(Qh, Kh, Vt, mask, Qh);
  dim3 g2(64, 8, 1);
  gemmk<64, 1><<<g2, 256, 0, stream>>>(Qh, Qh, Qh, Wo, Wo, Wo, d_out, d_out,
                                       d_out, dflag);
}